// Round 1
// baseline (245.734 us; speedup 1.0000x reference)
//
#include <hip/hip_runtime.h>
#include <math.h>

// Problem constants
#define KK 378            // crop size
#define HH 384            // full image H=W
#define NIMG 32           // batch
#define TILE 63           // 378 = 6*63
#define TPD 6             // tiles per dim
#define TPI 36            // tiles per image
#define NBLK (NIMG*TPI)   // 1152 stage-1 blocks
#define HALO 69           // 63 + 6 (shift halo)
#define NSH 49            // 7*7 shifts
#define NQ 5              // cnt, s1m, s1, s2, sabs
#define NTOT 4572288.0    // 32*378*378

__global__ __launch_bounds__(256) void mm_stage1(
    const float* __restrict__ pred, const float* __restrict__ targ,
    float* __restrict__ part)
{
    __shared__ float s_targ[HALO * HALO];      // 19044 B
    __shared__ float s_red[NSH][4][NQ];        // 3920 B

    const int bid  = blockIdx.x;
    const int img  = bid / TPI;
    const int tile = bid - img * TPI;
    const int tr   = (tile / TPD) * TILE;      // tile top row (output coords)
    const int tc   = (tile % TPD) * TILE;      // tile left col
    const int tid  = threadIdx.x;

    const float* timg = targ + (size_t)img * HH * HH;
    const float* pimg = pred + (size_t)img * HH * HH;

    // Stage target tile (with +6 halo; rows tr..tr+68 <= 383 always in-bounds)
    for (int i = tid; i < HALO * HALO; i += 256) {
        int r = i / HALO, c = i - r * HALO;
        s_targ[i] = timg[(tr + r) * HH + (tc + c)];
    }

    // Per-thread element set: 16 elements, strided by 256 over the 63*63 tile.
    float p[16], w[16];
    int   toff[16];
#pragma unroll
    for (int k = 0; k < 16; ++k) {
        int idx = tid + k * 256;
        float wv = (idx < TILE * TILE) ? 1.0f : 0.0f;
        int idxc = (idx < TILE * TILE) ? idx : 0;    // safe address for dead lanes
        int r = idxc / TILE, c = idxc - r * TILE;
        toff[k] = r * HALO + c;
        p[k] = pimg[(3 + tr + r) * HH + (3 + tc + c)];
        w[k] = wv;
    }
    __syncthreads();

    const int wave = tid >> 6;
    const int lane = tid & 63;

    for (int s = 0; s < NSH; ++s) {
        int u = s / 7, v = s - u * 7;
        int soff = u * HALO + v;
        float cnt = 0.f, s1m = 0.f, s1 = 0.f, s2 = 0.f, sab = 0.f;
#pragma unroll
        for (int k = 0; k < 16; ++k) {
            float t  = s_targ[toff[k] + soff];
            float d  = t - p[k];
            float dw = d * w[k];                     // zero for dead lanes
            float m  = (t > 5.0f) ? w[k] : 0.0f;     // mask * validity
            cnt += m;
            s1m  = fmaf(m, d, s1m);
            s1  += dw;
            s2   = fmaf(dw, d, s2);                  // w*d*d (w in {0,1})
            sab += fabsf(dw);
        }
        // 64-lane butterfly reduce
#pragma unroll
        for (int off = 32; off > 0; off >>= 1) {
            cnt += __shfl_xor(cnt, off);
            s1m += __shfl_xor(s1m, off);
            s1  += __shfl_xor(s1,  off);
            s2  += __shfl_xor(s2,  off);
            sab += __shfl_xor(sab, off);
        }
        if (lane == 0) {
            s_red[s][wave][0] = cnt;
            s_red[s][wave][1] = s1m;
            s_red[s][wave][2] = s1;
            s_red[s][wave][3] = s2;
            s_red[s][wave][4] = sab;
        }
    }
    __syncthreads();

    // 245 partials per block -> part[(s*5+q)][bid]
    if (tid < NSH * NQ) {
        float v = s_red[tid / NQ][0][tid % NQ] + s_red[tid / NQ][1][tid % NQ]
                + s_red[tid / NQ][2][tid % NQ] + s_red[tid / NQ][3][tid % NQ];
        part[(size_t)tid * NBLK + bid] = v;
    }
}

__global__ __launch_bounds__(256) void mm_stage2(
    const float* __restrict__ part, float* __restrict__ out)
{
    __shared__ double s_acc[NSH * NQ];
    const int tid = threadIdx.x;
    if (tid < NSH * NQ) {
        const float* pp = part + (size_t)tid * NBLK;
        // 4-way ILP double accumulation over 1152 block partials
        double a0 = 0, a1 = 0, a2 = 0, a3 = 0;
        for (int i = 0; i < NBLK; i += 4) {
            a0 += (double)pp[i + 0];
            a1 += (double)pp[i + 1];
            a2 += (double)pp[i + 2];
            a3 += (double)pp[i + 3];
        }
        s_acc[tid] = (a0 + a1) + (a2 + a3);
    }
    __syncthreads();
    if (tid == 0) {
        double best = 1e300; int bi = 0;
        for (int s = 0; s < NSH; ++s) {
            double cnt = s_acc[s * NQ + 0];
            double s1m = s_acc[s * NQ + 1];
            double s1  = s_acc[s * NQ + 2];
            double s2  = s_acc[s * NQ + 3];
            double b   = s1m / cnt;
            double cmse = (s2 - 2.0 * b * s1 + NTOT * b * b) / cnt;
            if (cmse < best) { best = cmse; bi = s; }   // strict '<' => first min (jnp.argmin)
        }
        out[0] = (float)(-10.0 * log10(best));
        out[1] = (float)(s_acc[bi * NQ + 4] / NTOT);
    }
}

extern "C" void kernel_launch(void* const* d_in, const int* in_sizes, int n_in,
                              void* d_out, int out_size, void* d_ws, size_t ws_size,
                              hipStream_t stream) {
    const float* pred = (const float*)d_in[0];
    const float* targ = (const float*)d_in[1];
    // d_in[2] (blended_target) is unused by the reference.
    float* part = (float*)d_ws;   // needs 245 * 1152 * 4 B = 1,128,960 B
    mm_stage1<<<NBLK, 256, 0, stream>>>(pred, targ, part);
    mm_stage2<<<1, 256, 0, stream>>>(part, (float*)d_out);
}

// Round 3
// 221.974 us; speedup vs baseline: 1.1070x; 1.1070x over previous
//
#include <hip/hip_runtime.h>
#include <math.h>

#define HH 384
#define H2 (HH*HH)
#define NIMG 32
#define KK 378
#define NSH 49
#define NTOTD 4572288.0   // 32*378*378

// ---- stage1 (correlation) geometry ----
#define SEGW 14           // cols per thread
#define NSEG 27           // 27*14 = 378
#define NSLOT 9           // row slots
#define GR 2              // rows per slot
#define TR 18             // tile rows = NSLOT*GR
#define NTILE 21          // 378/18
#define NBLK1 (NIMG*NTILE)   // 672
#define NACT (NSEG*NSLOT)    // 243 active threads
#define LDS_STRIDE 386       // 384 + 2 pad (bank spread)

typedef float v2f __attribute__((ext_vector_type(2)));

// ---- workspace layout (floats) ----
#define OFF_PART   0                       // [100][672]
#define OFF_ROWOUT (OFF_PART + 100*NBLK1)  // [12288][52]
#define OFF_HEAD   (OFF_ROWOUT + 12288*52) // [32][7][6][4]
#define OFF_TAIL   (OFF_HEAD + 32*7*6*4)   // [32][7][6][4]
#define OFF_COLSUM (OFF_TAIL + 32*7*6*4)   // [32][7][4] doubles (1792 floats)
#define OFF_MISC   (OFF_COLSUM + 224*4*2)  // int idx

// Canonical GCN wave64 sum: result in lane 63.
__device__ __forceinline__ float wred(float x) {
    x += __int_as_float(__builtin_amdgcn_update_dpp(0, __float_as_int(x), 0x111, 0xf, 0xf, true));
    x += __int_as_float(__builtin_amdgcn_update_dpp(0, __float_as_int(x), 0x112, 0xf, 0xf, true));
    x += __int_as_float(__builtin_amdgcn_update_dpp(0, __float_as_int(x), 0x114, 0xf, 0xf, true));
    x += __int_as_float(__builtin_amdgcn_update_dpp(0, __float_as_int(x), 0x118, 0xf, 0xf, true));
    x += __int_as_float(__builtin_amdgcn_update_dpp(0, __float_as_int(x), 0x142, 0xa, 0xf, true));
    x += __int_as_float(__builtin_amdgcn_update_dpp(0, __float_as_int(x), 0x143, 0xc, 0xf, true));
    return x;
}

// ---------------- stage1: tp/mp correlations (+ Sp, Sp2) ----------------
__global__ __launch_bounds__(256) void k_corr(
    const float* __restrict__ pred, const float* __restrict__ targ,
    float* __restrict__ part)
{
    __shared__ v2f lds_t[(TR + 6) * LDS_STRIDE];  // 24 rows x 386, (t, mask)
    __shared__ float red[100];

    const int bid = blockIdx.x;
    const int img = bid / NTILE;
    const int tile = bid - img * NTILE;
    const int r0 = tile * TR;
    const int tid = threadIdx.x;
    const int lane = tid & 63;

    if (tid < 100) red[tid] = 0.0f;

    // stage (t, m) rows r0..r0+23, full 384 cols, float4-vectorized
    const float* timg = targ + (size_t)img * H2;
    for (int k = 0; k < 9; ++k) {                  // 24*96 = 2304 float4 units
        int i = tid + k * 256;
        int r = i / 96, c4 = (i - r * 96) * 4;
        const float4 t4 = *reinterpret_cast<const float4*>(timg + (r0 + r) * HH + c4);
        int base = r * LDS_STRIDE + c4;
        lds_t[base + 0] = (v2f){t4.x, t4.x > 5.0f ? 1.0f : 0.0f};
        lds_t[base + 1] = (v2f){t4.y, t4.y > 5.0f ? 1.0f : 0.0f};
        lds_t[base + 2] = (v2f){t4.z, t4.z > 5.0f ? 1.0f : 0.0f};
        lds_t[base + 3] = (v2f){t4.w, t4.w > 5.0f ? 1.0f : 0.0f};
    }

    // thread -> (slot, seg); clamp dummies (tid>=243), mask later
    const bool valid = tid < NACT;
    int seg  = valid ? tid % NSEG : NSEG - 1;
    int slot = valid ? tid / NSEG : NSLOT - 1;
    const int c0 = seg * SEGW;
    const int slot2 = slot * GR;

    // p in registers (+ Sp, Sp2)
    float p_[GR][SEGW];
    float sp = 0.0f, sp2 = 0.0f;
    const float* pimg = pred + (size_t)img * H2;
#pragma unroll
    for (int dr = 0; dr < GR; ++dr) {
        const float* prow = pimg + (size_t)(3 + r0 + slot2 + dr) * HH + 3 + c0;
#pragma unroll
        for (int c = 0; c < SEGW; ++c) {
            float pv = prow[c];
            p_[dr][c] = pv;
            sp += pv;
            sp2 = fmaf(pv, pv, sp2);
        }
    }

    v2f acc[NSH];
#pragma unroll
    for (int i = 0; i < NSH; ++i) acc[i] = (v2f){0.0f, 0.0f};

    __syncthreads();

    // sliding-window correlation: 8 absolute rows serve u = g - dr
#pragma unroll
    for (int g = 0; g < GR + 6; ++g) {
        v2f win[SEGW + 6];
        const int wbase = (slot2 + g) * LDS_STRIDE + c0;
#pragma unroll
        for (int c = 0; c < SEGW + 6; ++c) win[c] = lds_t[wbase + c];
#pragma unroll
        for (int dr = 0; dr < GR; ++dr) {
            const int u = g - dr;
            if (u < 0 || u > 6) continue;          // folds at compile time
#pragma unroll
            for (int c = 0; c < SEGW; ++c) {
                const float pv = p_[dr][c];
                const v2f pvv = (v2f){pv, pv};
#pragma unroll
                for (int v = 0; v < 7; ++v)
                    acc[u * 7 + v] += win[v + c] * pvv;   // (t*p, m*p)
            }
        }
        __builtin_amdgcn_sched_barrier(0);   // contain register pressure per g
    }

    // mask dummy threads, reduce once per block
    const float vf = valid ? 1.0f : 0.0f;
    sp *= vf; sp2 *= vf;
#pragma unroll
    for (int i = 0; i < NSH; ++i) {
        float rx = wred(acc[i].x * vf);
        float ry = wred(acc[i].y * vf);
        if (lane == 63) { atomicAdd(&red[2 * i], rx); atomicAdd(&red[2 * i + 1], ry); }
    }
    {
        float rs = wred(sp), rs2 = wred(sp2);
        if (lane == 63) { atomicAdd(&red[98], rs); atomicAdd(&red[99], rs2); }
    }
    __syncthreads();
    if (tid < 100) part[(size_t)tid * NBLK1 + bid] = red[tid];
}

// ---------------- kA: per-row sums + border raws ----------------
// rowout[row][52]: [0..3]=R_q ; [4+x*4+q] x<6 raw left ; [28+(x-378)*4+q] raw right
__global__ __launch_bounds__(256) void k_rows(
    const float* __restrict__ targ, float* __restrict__ rowout)
{
    const int tid = threadIdx.x;
    const int w = tid >> 6, lane = tid & 63;
    const int row = blockIdx.x * 4 + w;            // 0..12287
    const int img = row / HH, y = row - img * HH;
    const float* tr = targ + (size_t)img * H2 + (size_t)y * HH;
    float* ro = rowout + (size_t)row * 52;

    float s0 = 0, s1 = 0, s2 = 0, s3 = 0;
#pragma unroll
    for (int j = 0; j < 6; ++j) {
        int x = lane + 64 * j;
        float t = tr[x];
        float m = t > 5.0f ? 1.0f : 0.0f;
        float t2 = t * t, tm = t * m;
        s0 += t; s1 += t2; s2 += tm; s3 += m;
        if (j == 0 && lane < 6) {
            ro[4 + x * 4 + 0] = t; ro[4 + x * 4 + 1] = t2;
            ro[4 + x * 4 + 2] = tm; ro[4 + x * 4 + 3] = m;
        }
        if (j == 5 && lane >= 58) {
            int k = x - 378;
            ro[28 + k * 4 + 0] = t; ro[28 + k * 4 + 1] = t2;
            ro[28 + k * 4 + 2] = tm; ro[28 + k * 4 + 3] = m;
        }
    }
    s0 = wred(s0); s1 = wred(s1); s2 = wred(s2); s3 = wred(s3);
    if (lane == 63) { ro[0] = s0; ro[1] = s1; ro[2] = s2; ro[3] = s3; }
}

// ---------------- kB: per-(img,v) column sums + border rowwins ----------------
__global__ __launch_bounds__(256) void k_cols(
    const float* __restrict__ rowout, double* __restrict__ colsum,
    float* __restrict__ headw, float* __restrict__ tailw)
{
    __shared__ double sd[256][4];
    const int img = blockIdx.x / 7, v = blockIdx.x - img * 7;
    const int tid = threadIdx.x;
    double a[4] = {0, 0, 0, 0};

    for (int y = tid; y < HH; y += 256) {
        const float* rp = rowout + ((size_t)img * HH + y) * 52;
        float rw[4];
#pragma unroll
        for (int q = 0; q < 4; ++q) rw[q] = rp[q];
        for (int j = 0; j < v; ++j)
#pragma unroll
            for (int q = 0; q < 4; ++q) rw[q] -= rp[4 + j * 4 + q];
        for (int k = v; k < 6; ++k)
#pragma unroll
            for (int q = 0; q < 4; ++q) rw[q] -= rp[28 + k * 4 + q];
#pragma unroll
        for (int q = 0; q < 4; ++q) a[q] += (double)rw[q];
        if (y < 6) {
#pragma unroll
            for (int q = 0; q < 4; ++q)
                headw[(((size_t)img * 7 + v) * 6 + y) * 4 + q] = rw[q];
        }
        if (y >= KK) {
#pragma unroll
            for (int q = 0; q < 4; ++q)
                tailw[(((size_t)img * 7 + v) * 6 + (y - KK)) * 4 + q] = rw[q];
        }
    }
#pragma unroll
    for (int q = 0; q < 4; ++q) sd[tid][q] = a[q];
    __syncthreads();
    if (tid < 4) {
        double t = 0;
        for (int i = 0; i < 256; ++i) t += sd[i][tid];
        colsum[((size_t)img * 7 + v) * 4 + tid] = t;
    }
}

// ---------------- kC: final combine, cmse argmin, cPSNR ----------------
__global__ __launch_bounds__(256) void k_comb(
    const float* __restrict__ part, const double* __restrict__ colsum,
    const float* __restrict__ headw, const float* __restrict__ tailw,
    float* __restrict__ out, int* __restrict__ misc)
{
    __shared__ double sd[200];
    __shared__ double corrD[100];
    __shared__ double Wd[NSH][4];
    const int tid = threadIdx.x;

    if (tid < 200) {                        // reduce 672 block partials, 2 halves
        int i = tid >> 1, h = tid & 1;
        const float* pp = part + (size_t)i * NBLK1 + h * 336;
        double s = 0;
        for (int b = 0; b < 336; ++b) s += (double)pp[b];
        sd[tid] = s;
    }
    __syncthreads();
    if (tid < 100) corrD[tid] = sd[2 * tid] + sd[2 * tid + 1];

    if (tid < 196) {                        // window sums W_q[u,v]
        int s = tid >> 2, q = tid & 3;
        int u = s / 7, v = s - u * 7;
        double a = 0;
        for (int img = 0; img < NIMG; ++img) {
            a += colsum[((size_t)img * 7 + v) * 4 + q];
            const float* hw = headw + (((size_t)img * 7 + v) * 6) * 4;
            const float* tw = tailw + (((size_t)img * 7 + v) * 6) * 4;
            for (int y = 0; y < u; ++y) a -= (double)hw[y * 4 + q];
            for (int k = u; k < 6; ++k) a -= (double)tw[k * 4 + q];
        }
        Wd[s][q] = a;
    }
    __syncthreads();

    if (tid == 0) {
        const double Sp = corrD[98], Sp2 = corrD[99];
        double best = 1e300; int bi = 0;
        for (int s = 0; s < NSH; ++s) {
            double tp = corrD[2 * s], mp = corrD[2 * s + 1];
            double Wt = Wd[s][0], Wt2 = Wd[s][1], Wtm = Wd[s][2], cnt = Wd[s][3];
            double b = (Wtm - mp) / cnt;
            double s1 = Wt - Sp;
            double s2t = Wt2 - 2.0 * tp + Sp2;
            double cmse = (s2t - 2.0 * b * s1 + NTOTD * b * b) / cnt;
            if (cmse < best) { best = cmse; bi = s; }   // first-min like jnp.argmin
        }
        out[0] = (float)(-10.0 * log10(best));
        out[1] = 0.0f;                       // MAE accumulator (d_out re-poisoned)
        misc[0] = bi;
    }
}

// ---------------- kD: MAE at best shift ----------------
__global__ __launch_bounds__(256) void k_mae(
    const float* __restrict__ pred, const float* __restrict__ targ,
    const int* __restrict__ misc, float* __restrict__ out)
{
    __shared__ float ps[4];
    const int idx = misc[0];
    const int u = idx / 7, v = idx - u * 7;
    const int tid = threadIdx.x;
    const int lane = tid & 63, w = tid >> 6;
    const int total = NIMG * KK * KK;
    float s = 0.0f;
    for (int i = blockIdx.x * 256 + tid; i < total; i += gridDim.x * 256) {
        int img = i / (KK * KK);
        int rem = i - img * (KK * KK);
        int r = rem / KK, c = rem - r * KK;
        float t = targ[(size_t)img * H2 + (size_t)(r + u) * HH + (c + v)];
        float p = pred[(size_t)img * H2 + (size_t)(r + 3) * HH + (c + 3)];
        s += fabsf(t - p);
    }
    s = wred(s);
    if (lane == 63) ps[w] = s;
    __syncthreads();
    if (tid == 0)
        atomicAdd(&out[1], (ps[0] + ps[1] + ps[2] + ps[3]) * (float)(1.0 / NTOTD));
}

extern "C" void kernel_launch(void* const* d_in, const int* in_sizes, int n_in,
                              void* d_out, int out_size, void* d_ws, size_t ws_size,
                              hipStream_t stream) {
    const float* pred = (const float*)d_in[0];
    const float* targ = (const float*)d_in[1];
    float* w = (float*)d_ws;                 // needs ~2.88 MB
    float* part    = w + OFF_PART;
    float* rowout  = w + OFF_ROWOUT;
    float* headw   = w + OFF_HEAD;
    float* tailw   = w + OFF_TAIL;
    double* colsum = (double*)(w + OFF_COLSUM);
    int*   misc    = (int*)(w + OFF_MISC);
    float* out = (float*)d_out;

    k_corr<<<NBLK1, 256, 0, stream>>>(pred, targ, part);
    k_rows<<<12288 / 4, 256, 0, stream>>>(targ, rowout);
    k_cols<<<NIMG * 7, 256, 0, stream>>>(rowout, colsum, headw, tailw);
    k_comb<<<1, 256, 0, stream>>>(part, colsum, headw, tailw, out, misc);
    k_mae<<<1024, 256, 0, stream>>>(pred, targ, misc, out);
}

// Round 4
// 180.523 us; speedup vs baseline: 1.3612x; 1.2296x over previous
//
#include <hip/hip_runtime.h>
#include <math.h>

#define HH 384
#define H2 (HH*HH)
#define NIMG 32
#define KK 378
#define NSH 49
#define NTOTD 4572288.0   // 32*378*378

// ---- stage1 (correlation) geometry ----
#define SEGW 14           // cols per thread
#define NSEG 27           // 27*14 = 378
#define NSLOT 9           // row slots
#define GR 2              // rows per slot
#define TR 18             // tile rows = NSLOT*GR
#define NTILE 21          // 378/18
#define NBLK1 (NIMG*NTILE)   // 672
#define NACT (NSEG*NSLOT)    // 243 active threads
#define LDS_STRIDE 386       // 384 + 2 pad

typedef float v2f __attribute__((ext_vector_type(2)));

// ---- workspace layout (float units; double regions 8B-aligned) ----
#define OFF_PART   0                         // [100][672] float
#define OFF_ROWOUT (OFF_PART + 100*NBLK1)    // [12288][52] float
#define OFF_WPART  (OFF_ROWOUT + 12288*52)   // [49][4][32] double (12544 floats)
#define OFF_CORRD  (OFF_WPART + 12544)       // [100] double (200 floats)
#define OFF_MISC   (OFF_CORRD + 200)         // int idx

// Canonical GCN wave64 sum: result in lane 63.
__device__ __forceinline__ float wred(float x) {
    x += __int_as_float(__builtin_amdgcn_update_dpp(0, __float_as_int(x), 0x111, 0xf, 0xf, true));
    x += __int_as_float(__builtin_amdgcn_update_dpp(0, __float_as_int(x), 0x112, 0xf, 0xf, true));
    x += __int_as_float(__builtin_amdgcn_update_dpp(0, __float_as_int(x), 0x114, 0xf, 0xf, true));
    x += __int_as_float(__builtin_amdgcn_update_dpp(0, __float_as_int(x), 0x118, 0xf, 0xf, true));
    x += __int_as_float(__builtin_amdgcn_update_dpp(0, __float_as_int(x), 0x142, 0xa, 0xf, true));
    x += __int_as_float(__builtin_amdgcn_update_dpp(0, __float_as_int(x), 0x143, 0xc, 0xf, true));
    return x;
}

// ---------------- k_corr: tp/mp correlations (+ Sp, Sp2) ----------------
__global__ __launch_bounds__(256) void k_corr(
    const float* __restrict__ pred, const float* __restrict__ targ,
    float* __restrict__ part)
{
    __shared__ v2f lds_t[(TR + 6) * LDS_STRIDE];
    __shared__ float red[100];

    const int bid = blockIdx.x;
    const int img = bid / NTILE;
    const int tile = bid - img * NTILE;
    const int r0 = tile * TR;
    const int tid = threadIdx.x;
    const int lane = tid & 63;

    if (tid < 100) red[tid] = 0.0f;

    const float* timg = targ + (size_t)img * H2;
    for (int k = 0; k < 9; ++k) {
        int i = tid + k * 256;
        int r = i / 96, c4 = (i - r * 96) * 4;
        const float4 t4 = *reinterpret_cast<const float4*>(timg + (r0 + r) * HH + c4);
        int base = r * LDS_STRIDE + c4;
        lds_t[base + 0] = (v2f){t4.x, t4.x > 5.0f ? 1.0f : 0.0f};
        lds_t[base + 1] = (v2f){t4.y, t4.y > 5.0f ? 1.0f : 0.0f};
        lds_t[base + 2] = (v2f){t4.z, t4.z > 5.0f ? 1.0f : 0.0f};
        lds_t[base + 3] = (v2f){t4.w, t4.w > 5.0f ? 1.0f : 0.0f};
    }

    const bool valid = tid < NACT;
    int seg  = valid ? tid % NSEG : NSEG - 1;
    int slot = valid ? tid / NSEG : NSLOT - 1;
    const int c0 = seg * SEGW;
    const int slot2 = slot * GR;

    float p_[GR][SEGW];
    float sp = 0.0f, sp2 = 0.0f;
    const float* pimg = pred + (size_t)img * H2;
#pragma unroll
    for (int dr = 0; dr < GR; ++dr) {
        const float* prow = pimg + (size_t)(3 + r0 + slot2 + dr) * HH + 3 + c0;
#pragma unroll
        for (int c = 0; c < SEGW; ++c) {
            float pv = prow[c];
            p_[dr][c] = pv;
            sp += pv;
            sp2 = fmaf(pv, pv, sp2);
        }
    }

    v2f acc[NSH];
#pragma unroll
    for (int i = 0; i < NSH; ++i) acc[i] = (v2f){0.0f, 0.0f};

    __syncthreads();

#pragma unroll
    for (int g = 0; g < GR + 6; ++g) {
        v2f win[SEGW + 6];
        const int wbase = (slot2 + g) * LDS_STRIDE + c0;
#pragma unroll
        for (int c = 0; c < SEGW + 6; ++c) win[c] = lds_t[wbase + c];
#pragma unroll
        for (int dr = 0; dr < GR; ++dr) {
            const int u = g - dr;
            if (u < 0 || u > 6) continue;
#pragma unroll
            for (int c = 0; c < SEGW; ++c) {
                const float pv = p_[dr][c];
                const v2f pvv = (v2f){pv, pv};
#pragma unroll
                for (int v = 0; v < 7; ++v)
                    acc[u * 7 + v] += win[v + c] * pvv;
            }
        }
        __builtin_amdgcn_sched_barrier(0);
    }

    const float vf = valid ? 1.0f : 0.0f;
    sp *= vf; sp2 *= vf;
#pragma unroll
    for (int i = 0; i < NSH; ++i) {
        float rx = wred(acc[i].x * vf);
        float ry = wred(acc[i].y * vf);
        if (lane == 63) { atomicAdd(&red[2 * i], rx); atomicAdd(&red[2 * i + 1], ry); }
    }
    {
        float rs = wred(sp), rs2 = wred(sp2);
        if (lane == 63) { atomicAdd(&red[98], rs); atomicAdd(&red[99], rs2); }
    }
    __syncthreads();
    if (tid < 100) part[(size_t)tid * NBLK1 + bid] = red[tid];
}

// ---------------- k_rows: per-row sums + border raws ----------------
__global__ __launch_bounds__(256) void k_rows(
    const float* __restrict__ targ, float* __restrict__ rowout)
{
    const int tid = threadIdx.x;
    const int w = tid >> 6, lane = tid & 63;
    const int row = blockIdx.x * 4 + w;
    const int img = row / HH, y = row - img * HH;
    const float* tr = targ + (size_t)img * H2 + (size_t)y * HH;
    float* ro = rowout + (size_t)row * 52;

    float s0 = 0, s1 = 0, s2 = 0, s3 = 0;
#pragma unroll
    for (int j = 0; j < 6; ++j) {
        int x = lane + 64 * j;
        float t = tr[x];
        float m = t > 5.0f ? 1.0f : 0.0f;
        float t2 = t * t, tm = t * m;
        s0 += t; s1 += t2; s2 += tm; s3 += m;
        if (j == 0 && lane < 6) {
            ro[4 + x * 4 + 0] = t; ro[4 + x * 4 + 1] = t2;
            ro[4 + x * 4 + 2] = tm; ro[4 + x * 4 + 3] = m;
        }
        if (j == 5 && lane >= 58) {
            int k = x - 378;
            ro[28 + k * 4 + 0] = t; ro[28 + k * 4 + 1] = t2;
            ro[28 + k * 4 + 2] = tm; ro[28 + k * 4 + 3] = m;
        }
    }
    s0 = wred(s0); s1 = wred(s1); s2 = wred(s2); s3 = wred(s3);
    if (lane == 63) { ro[0] = s0; ro[1] = s1; ro[2] = s2; ro[3] = s3; }
}

// ---------------- k_cols: per-(img,v) window sums -> wpart ----------------
// One thread per row y. wpart[(u*7+v)*4+q][img] (doubles).
__global__ __launch_bounds__(384) void k_cols(
    const float* __restrict__ rowout, double* __restrict__ wpart)
{
    __shared__ double sd[384][4];          // 12 KB
    __shared__ float hb[6][4], tb[6][4];
    const int img = blockIdx.x / 7, v = blockIdx.x - img * 7;
    const int y = threadIdx.x;

    const float* rp = rowout + ((size_t)img * HH + y) * 52;
    float4 r4[13];
#pragma unroll
    for (int i = 0; i < 13; ++i) r4[i] = reinterpret_cast<const float4*>(rp)[i];
    const float* rf = reinterpret_cast<const float*>(r4);

    float rw[4];
#pragma unroll
    for (int q = 0; q < 4; ++q) rw[q] = rf[q];
    for (int j = 0; j < v; ++j)
#pragma unroll
        for (int q = 0; q < 4; ++q) rw[q] -= rf[4 + j * 4 + q];
    for (int k = v; k < 6; ++k)
#pragma unroll
        for (int q = 0; q < 4; ++q) rw[q] -= rf[28 + k * 4 + q];

#pragma unroll
    for (int q = 0; q < 4; ++q) sd[y][q] = (double)rw[q];
    if (y < 6)
#pragma unroll
        for (int q = 0; q < 4; ++q) hb[y][q] = rw[q];
    if (y >= KK)
#pragma unroll
        for (int q = 0; q < 4; ++q) tb[y - KK][q] = rw[q];
    __syncthreads();

    // deterministic tree over 384: s = 192,96,48,24,12,6,3; remainder 3 summed below
    for (int s = 192; s >= 3; s >>= 1) {
        if (y < s)
#pragma unroll
            for (int q = 0; q < 4; ++q) sd[y][q] += sd[y + s][q];
        __syncthreads();
    }

    if (y < 28) {
        int u = y >> 2, q = y & 3;
        double a = sd[0][q] + sd[1][q] + sd[2][q];
        for (int j = 0; j < u; ++j) a -= (double)hb[j][q];
        for (int k = u; k < 6; ++k) a -= (double)tb[k][q];
        wpart[((size_t)(u * 7 + v) * 4 + q) * 32 + img] = a;
    }
}

// ---------------- k_red: reduce part[100][672] -> corrD[100] doubles ----------------
__global__ __launch_bounds__(256) void k_red(
    const float* __restrict__ part, double* __restrict__ corrD)
{
    __shared__ double sd[256];
    const int q = blockIdx.x;
    const int t = threadIdx.x;
    const float* pp = part + (size_t)q * NBLK1;
    double a = (double)pp[t] + (double)pp[t + 256];
    if (t < NBLK1 - 512) a += (double)pp[t + 512];
    sd[t] = a;
    __syncthreads();
    for (int s = 128; s > 0; s >>= 1) {
        if (t < s) sd[t] += sd[t + s];
        __syncthreads();
    }
    if (t == 0) corrD[q] = sd[0];
}

// ---------------- k_fin: Wd, cmse argmin, cPSNR ----------------
__global__ __launch_bounds__(256) void k_fin(
    const double* __restrict__ corrD, const double* __restrict__ wpart,
    float* __restrict__ out, int* __restrict__ misc)
{
    __shared__ double Wd[NSH][4];
    __shared__ double cm[NSH];
    const int t = threadIdx.x;

    if (t < 196) {
        const double* wp = wpart + (size_t)t * 32;
        double a0 = 0, a1 = 0;
#pragma unroll
        for (int i = 0; i < 32; i += 2) { a0 += wp[i]; a1 += wp[i + 1]; }
        Wd[t >> 2][t & 3] = a0 + a1;
    }
    __syncthreads();
    if (t < NSH) {
        double tp = corrD[2 * t], mp = corrD[2 * t + 1];
        double Sp = corrD[98], Sp2 = corrD[99];
        double b = (Wd[t][2] - mp) / Wd[t][3];
        double s1 = Wd[t][0] - Sp;
        double s2t = Wd[t][1] - 2.0 * tp + Sp2;
        cm[t] = (s2t - 2.0 * b * s1 + NTOTD * b * b) / Wd[t][3];
    }
    __syncthreads();
    if (t == 0) {
        double best = cm[0]; int bi = 0;
        for (int s = 1; s < NSH; ++s)
            if (cm[s] < best) { best = cm[s]; bi = s; }   // first-min (jnp.argmin)
        out[0] = (float)(-10.0 * log10(best));
        out[1] = 0.0f;
        misc[0] = bi;
    }
}

// ---------------- k_mae: MAE at best shift ----------------
__global__ __launch_bounds__(256) void k_mae(
    const float* __restrict__ pred, const float* __restrict__ targ,
    const int* __restrict__ misc, float* __restrict__ out)
{
    __shared__ float ps[4];
    const int idx = misc[0];
    const int u = idx / 7, v = idx - u * 7;
    const int tid = threadIdx.x;
    const int lane = tid & 63, w = tid >> 6;
    const int total = NIMG * KK * KK;
    float s = 0.0f;
    for (int i = blockIdx.x * 256 + tid; i < total; i += gridDim.x * 256) {
        int img = i / (KK * KK);
        int rem = i - img * (KK * KK);
        int r = rem / KK, c = rem - r * KK;
        float t = targ[(size_t)img * H2 + (size_t)(r + u) * HH + (c + v)];
        float p = pred[(size_t)img * H2 + (size_t)(r + 3) * HH + (c + 3)];
        s += fabsf(t - p);
    }
    s = wred(s);
    if (lane == 63) ps[w] = s;
    __syncthreads();
    if (tid == 0)
        atomicAdd(&out[1], (ps[0] + ps[1] + ps[2] + ps[3]) * (float)(1.0 / NTOTD));
}

extern "C" void kernel_launch(void* const* d_in, const int* in_sizes, int n_in,
                              void* d_out, int out_size, void* d_ws, size_t ws_size,
                              hipStream_t stream) {
    const float* pred = (const float*)d_in[0];
    const float* targ = (const float*)d_in[1];
    float* w = (float*)d_ws;                 // needs ~2.88 MB
    float*  part   = w + OFF_PART;
    float*  rowout = w + OFF_ROWOUT;
    double* wpart  = (double*)(w + OFF_WPART);
    double* corrD  = (double*)(w + OFF_CORRD);
    int*    misc   = (int*)(w + OFF_MISC);
    float* out = (float*)d_out;

    k_corr<<<NBLK1, 256, 0, stream>>>(pred, targ, part);
    k_rows<<<12288 / 4, 256, 0, stream>>>(targ, rowout);
    k_cols<<<NIMG * 7, 384, 0, stream>>>(rowout, wpart);
    k_red<<<100, 256, 0, stream>>>(part, corrD);
    k_fin<<<1, 256, 0, stream>>>(corrD, wpart, out, misc);
    k_mae<<<1024, 256, 0, stream>>>(pred, targ, misc, out);
}